// Round 1
// baseline (1324.228 us; speedup 1.0000x reference)
//
#include <hip/hip_runtime.h>
#include <math.h>

// WindowAttention: B=2048, N=64, C=512, H=8, D=64.
// One block of 256 threads per (b,h). k2 (d_in[4]) is dead in the reference.
namespace {
constexpr int kB = 2048;
constexpr int kN = 64;
constexpr int kC = 512;
constexpr int kH = 8;
constexpr int kD = 64;
constexpr float kScale = 0.125f;   // HEAD_DIM^-0.5
}

__global__ __launch_bounds__(256, 2)
void winattn_fused(const float* __restrict__ q1,
                   const float* __restrict__ q2,
                   const float* __restrict__ k1,
                   const float* __restrict__ v1,
                   const float* __restrict__ bias_table,
                   const float* __restrict__ gating,
                   const int*   __restrict__ rel_index,
                   float* __restrict__ out)
{
  // 64 KB LDS total -> 2 blocks/CU. q/k arrays use a float4-slot XOR swizzle
  // (slot = c4 ^ (row&15)) so score-phase reads are bank-conflict-free.
  __shared__ __align__(16) float q1s[kN * kD];
  __shared__ __align__(16) float q2s[kN * kD];
  __shared__ __align__(16) float k1s[kN * kD];
  __shared__ __align__(16) float v1s[kN * kD];   // unswizzled (2-way = free)

  const int t  = threadIdx.x;
  const int bh = blockIdx.x;
  const int b  = bh >> 3;
  const int h  = bh & 7;

  const size_t base = (size_t)b * (kN * kC) + (size_t)h * kD;
  const float* __restrict__ gq1 = q1 + base;
  const float* __restrict__ gq2 = q2 + base;
  const float* __restrict__ gk1 = k1 + base;
  const float* __restrict__ gv1 = v1 + base;

  // ---- Stage tiles: 1024 float4 per tensor, 4 iterations of 256 threads ----
#pragma unroll
  for (int i = 0; i < 4; ++i) {
    const int idx = i * 256 + t;
    const int row = idx >> 4;        // 0..63
    const int c4  = idx & 15;        // float4 slot 0..15
    const int sw  = (c4 ^ (row & 15)) * 4;
    const float4 a  = *(const float4*)(gq1 + row * kC + c4 * 4);
    const float4 bq = *(const float4*)(gq2 + row * kC + c4 * 4);
    const float4 kk = *(const float4*)(gk1 + row * kC + c4 * 4);
    const float4 vv = *(const float4*)(gv1 + row * kC + c4 * 4);
    *(float4*)&q1s[row * 64 + sw] =
        make_float4(a.x * kScale, a.y * kScale, a.z * kScale, a.w * kScale);
    *(float4*)&q2s[row * 64 + sw] =
        make_float4(bq.x * kScale, bq.y * kScale, bq.z * kScale, bq.w * kScale);
    *(float4*)&k1s[row * 64 + sw] = kk;
    *(float4*)&v1s[row * 64 + c4 * 4] = vv;
  }

  const int r  = t >> 2;   // my row 0..63
  const int cq = t & 3;    // my column-chunk: columns m = cq + 4*j

  // ---- Prefetch bias for my 16 columns (L1-resident after first touch) ----
  float bias_r[16];
#pragma unroll
  for (int j = 0; j < 16; ++j) {
    const int m  = cq + 4 * j;
    const int bi = rel_index[r * 64 + m];
    bias_r[j] = bias_table[bi * kH + h];
  }
  const float gp = gating[h];
  const float g  = 1.0f / (1.0f + __expf(-gp));   // sigmoid

  __syncthreads();

  // ---- Scores: s1/s2[j] = bias + (q_row . k_row_m), m = cq + 4*j ----
  float s1[16], s2[16];
#pragma unroll
  for (int j = 0; j < 16; ++j) { s1[j] = bias_r[j]; s2[j] = bias_r[j]; }

  const int rsw = r & 15;
#pragma unroll
  for (int d4 = 0; d4 < 16; ++d4) {
    const float4 qa = *(const float4*)&q1s[r * 64 + ((d4 ^ rsw) * 4)];
    const float4 qb = *(const float4*)&q2s[r * 64 + ((d4 ^ rsw) * 4)];
#pragma unroll
    for (int j = 0; j < 16; ++j) {
      const int m = cq + 4 * j;
      const float4 kv = *(const float4*)&k1s[m * 64 + ((d4 ^ (m & 15)) * 4)];
      s1[j] += qa.x * kv.x + qa.y * kv.y + qa.z * kv.z + qa.w * kv.w;
      s2[j] += qb.x * kv.x + qb.y * kv.y + qb.z * kv.z + qb.w * kv.w;
    }
  }

  // ---- Dual softmax + gating, row spread across 4 adjacent lanes ----
  float mx1 = s1[0], mx2 = s2[0];
#pragma unroll
  for (int j = 1; j < 16; ++j) { mx1 = fmaxf(mx1, s1[j]); mx2 = fmaxf(mx2, s2[j]); }
  mx1 = fmaxf(mx1, __shfl_xor(mx1, 1, 64));
  mx1 = fmaxf(mx1, __shfl_xor(mx1, 2, 64));
  mx2 = fmaxf(mx2, __shfl_xor(mx2, 1, 64));
  mx2 = fmaxf(mx2, __shfl_xor(mx2, 2, 64));

  float sum1 = 0.0f, sum2 = 0.0f;
#pragma unroll
  for (int j = 0; j < 16; ++j) {
    const float e1 = __expf(s1[j] - mx1);
    const float e2 = __expf(s2[j] - mx2);
    s1[j] = e1; s2[j] = e2;
    sum1 += e1; sum2 += e2;
  }
  sum1 += __shfl_xor(sum1, 1, 64); sum1 += __shfl_xor(sum1, 2, 64);
  sum2 += __shfl_xor(sum2, 1, 64); sum2 += __shfl_xor(sum2, 2, 64);

  const float w1 = (1.0f - g) / sum1;
  const float w2 = g / sum2;

  float attnv[16];
  float rsum = 0.0f;
#pragma unroll
  for (int j = 0; j < 16; ++j) {
    attnv[j] = w1 * s1[j] + w2 * s2[j];
    rsum += attnv[j];
  }
  rsum += __shfl_xor(rsum, 1, 64);
  rsum += __shfl_xor(rsum, 2, 64);
  const float inv = 1.0f / rsum;   // renormalization folded into the store

  // ---- PV: x[d], d = cq*16 + j'. attn row exchanged lane-to-lane (bpermute),
  // no LDS round-trip for the attention matrix. ----
  float x[16];
#pragma unroll
  for (int j = 0; j < 16; ++j) x[j] = 0.0f;

  const int lane = t & 63;
  const int bl   = lane & 60;   // first of the 4 lanes holding my row
  const float* __restrict__ vbase = &v1s[cq * 16];
#pragma unroll
  for (int c2 = 0; c2 < 4; ++c2) {
#pragma unroll
    for (int mj = 0; mj < 16; ++mj) {
      const float a = __shfl(attnv[mj], bl + c2, 64);
      const int m = c2 + 4 * mj;
      const float* __restrict__ vrow = vbase + m * 64;
      const float4 v0 = *(const float4*)&vrow[0];
      const float4 v1r = *(const float4*)&vrow[4];
      const float4 v2 = *(const float4*)&vrow[8];
      const float4 v3 = *(const float4*)&vrow[12];
      x[0]  += a * v0.x;  x[1]  += a * v0.y;  x[2]  += a * v0.z;  x[3]  += a * v0.w;
      x[4]  += a * v1r.x; x[5]  += a * v1r.y; x[6]  += a * v1r.z; x[7]  += a * v1r.w;
      x[8]  += a * v2.x;  x[9]  += a * v2.y;  x[10] += a * v2.z;  x[11] += a * v2.w;
      x[12] += a * v3.x;  x[13] += a * v3.y;  x[14] += a * v3.z;  x[15] += a * v3.w;
    }
  }

  // ---- Store: out[b][r][h*64 + cq*16 + j'] ----
  float* __restrict__ gout = out + base + (size_t)r * kC + cq * 16;
#pragma unroll
  for (int j4 = 0; j4 < 4; ++j4) {
    *(float4*)&gout[j4 * 4] = make_float4(x[j4 * 4 + 0] * inv,
                                          x[j4 * 4 + 1] * inv,
                                          x[j4 * 4 + 2] * inv,
                                          x[j4 * 4 + 3] * inv);
  }
}

extern "C" void kernel_launch(void* const* d_in, const int* in_sizes, int n_in,
                              void* d_out, int out_size, void* d_ws, size_t ws_size,
                              hipStream_t stream) {
  const float* q1         = (const float*)d_in[0];
  const float* q2         = (const float*)d_in[1];
  const float* k1         = (const float*)d_in[2];
  const float* v1         = (const float*)d_in[3];
  // d_in[4] = k2: unused by the reference math.
  const float* bias_table = (const float*)d_in[5];
  const float* gating     = (const float*)d_in[6];
  const int*   rel_index  = (const int*)d_in[7];
  float* out = (float*)d_out;

  winattn_fused<<<dim3(kB * kH), dim3(256), 0, stream>>>(
      q1, q2, k1, v1, bias_table, gating, rel_index, out);
}